// Round 9
// baseline (164.293 us; speedup 1.0000x reference)
//
#include <hip/hip_runtime.h>

typedef __bf16 bf16x8 __attribute__((ext_vector_type(8)));
typedef float  f32x4  __attribute__((ext_vector_type(4)));
typedef float  f32x16 __attribute__((ext_vector_type(16)));

constexpr float K1   = 27.178297f;        // sqrt(512*log2 e); enc = exp2(-(K1*(x-c))^2)
constexpr float STEP = -K1 / 31.0f;       // centers[i] = i/31

// MFMA 32x32x16 bf16 layouts:
//   A-frag: lane l holds A[m=l&31][k=(l>>5)*8+j]   (k-mapping consistency A<->B is
//   B-frag: lane l holds B[k=(l>>5)*8+j][n=l&31]    what correctness relies on)
//   C/D   : lane l reg r holds D[ch=(r&3)+8*(r>>2)+4*(l>>5)][col=l&31]  (m74/m101)
// Transposed compute: D[ch][row] = W^T @ enc^T, row = l&31.
// k-permutation pi(16w + 8h + j) = 16w + (j&3) + 8*(j>>2) + 4h on W2/W3 rows makes
// the next layer's B-frag a pure in-lane repack: hf[w][j] = relu(acc[w>>1][8*(w&1)+j]).
// Biases enter via one extra K-tile: B = bconst (1.0 at slot h=0,j=0), A-frag row0 = b.
//
// ws frag map (1 KiB each): [0,28) W1(t,mt)=2t+mt; [28,30) b1(mt);
// [30,38) W2(w,mt)=30+2w+mt; [38,40) b2(mt); [40,48) W3(w,mt)=40+2w+mt; [48,50) b3(mt).

__global__ void prep_kernel(const float* __restrict__ W1, const float* __restrict__ b1,
                            const float* __restrict__ W2, const float* __restrict__ b2,
                            const float* __restrict__ W3, const float* __restrict__ b3,
                            bf16x8* __restrict__ ws)
{
    const int f = blockIdx.x;
    const int l = threadIdx.x;
    const int h = l >> 5, n = l & 31;
    bf16x8 v = {};
    if (f < 28) {
        const int t = f >> 1, mt = f & 1;
#pragma unroll
        for (int j = 0; j < 8; ++j)
            v[j] = (__bf16)W1[(16 * t + 8 * h + j) * 64 + 32 * mt + n];
    } else if (f < 30) {
        if (h == 0) v[0] = (__bf16)b1[32 * (f - 28) + n];
    } else if (f < 38) {
        const int w = (f - 30) >> 1, mt = (f - 30) & 1;
#pragma unroll
        for (int j = 0; j < 8; ++j)
            v[j] = (__bf16)W2[(16 * w + (j & 3) + 8 * (j >> 2) + 4 * h) * 64 + 32 * mt + n];
    } else if (f < 40) {
        if (h == 0) v[0] = (__bf16)b2[32 * (f - 38) + n];
    } else if (f < 48) {
        const int w = (f - 40) >> 1, mt = (f - 40) & 1;
#pragma unroll
        for (int j = 0; j < 8; ++j)
            v[j] = (__bf16)W3[(16 * w + (j & 3) + 8 * (j >> 2) + 4 * h) * 64 + 32 * mt + n];
    } else {
        if (h == 0) v[0] = (__bf16)b3[32 * (f - 48) + n];
    }
    ws[f * 64 + l] = v;
}

__device__ __forceinline__ void load_x(const float* __restrict__ pos,
                                       const float* __restrict__ wi,
                                       const float* __restrict__ rough,
                                       int row, float* x)
{
    x[0] = pos[row * 3 + 0]; x[1] = pos[row * 3 + 1]; x[2] = pos[row * 3 + 2];
    x[3] = wi[row * 3 + 0];  x[4] = wi[row * 3 + 1];  x[5] = wi[row * 3 + 2];
    x[6] = rough[row];
}

// 8 waves x 32 rows/iter x 4 iters = 1024 rows/block
__global__ __launch_bounds__(512, 4)
void cond_net_kernel(const float* __restrict__ pos, const float* __restrict__ wi,
                     const float* __restrict__ rough,
                     const bf16x8* __restrict__ ws,
                     float* __restrict__ out)
{
    __shared__ __align__(16) char lds[50 * 1024];

    const int tid = threadIdx.x;
    const int l = tid & 63, wv = tid >> 6, h = l >> 5, n = l & 31;

    // stage all 50 fragments via async global->LDS, lane-linear
    for (int fr = wv; fr < 50; fr += 8)
        __builtin_amdgcn_global_load_lds(
            (const __attribute__((address_space(1))) void*)(ws + fr * 64 + l),
            (__attribute__((address_space(3))) void*)(lds + fr * 1024),
            16, 0, 0);

    // bias B-frag: 1.0 at slot (h=0, j=0) only
    bf16x8 bconst = {};
    bconst[0] = (h == 0) ? (__bf16)1.0f : (__bf16)0.0f;

    const float hoff = STEP * (float)(8 * h);
    const int rbase = blockIdx.x * 1024 + wv * 32 + n;

    float xc[7];
    load_x(pos, wi, rough, rbase, xc);

    __syncthreads();   // drains global_load_lds + barrier

    unsigned int ldsoff = 0;
#pragma unroll 1
    for (int it = 0; it < 4; ++it) {
        asm volatile("" : "+v"(ldsoff));          // defeat LICM on LDS reads
        const char* lb = (const char*)lds + ldsoff + l * 16;

        // prefetch next iteration's inputs
        float xn[7];
        load_x(pos, wi, rough, rbase + ((it + 1) & 3) * 256, xn);

        float B0[7];
#pragma unroll
        for (int d = 0; d < 7; ++d)
            B0[d] = fmaf(K1, fminf(fmaxf(xc[d], 0.0f), 1.0f), hoff);

        // ---- layer 1: 14 K-tiles + bias tile ----
        f32x16 a1A = {}, a1B = {};
#pragma unroll
        for (int t = 0; t < 14; ++t) {
            const int kk = t >> 1, wh = t & 1;
            bf16x8 e;
#pragma unroll
            for (int j = 0; j < 8; ++j) {
                const float d = fmaf((float)(16 * wh + j), STEP, B0[kk]);
                e[j] = (__bf16)__builtin_amdgcn_exp2f(-(d * d));
            }
            a1A = __builtin_amdgcn_mfma_f32_32x32x16_bf16(
                *(const bf16x8*)(lb + (2 * t + 0) * 1024), e, a1A, 0, 0, 0);
            a1B = __builtin_amdgcn_mfma_f32_32x32x16_bf16(
                *(const bf16x8*)(lb + (2 * t + 1) * 1024), e, a1B, 0, 0, 0);
        }
        a1A = __builtin_amdgcn_mfma_f32_32x32x16_bf16(
            *(const bf16x8*)(lb + 28 * 1024), bconst, a1A, 0, 0, 0);
        a1B = __builtin_amdgcn_mfma_f32_32x32x16_bf16(
            *(const bf16x8*)(lb + 29 * 1024), bconst, a1B, 0, 0, 0);

        // ---- relu + in-lane repack: hf[w][j] = relu(acc[w>>1][8*(w&1)+j]) ----
        bf16x8 h1f[4];
#pragma unroll
        for (int w = 0; w < 4; ++w)
#pragma unroll
            for (int j = 0; j < 8; ++j)
                h1f[w][j] = (__bf16)fmaxf(((w >> 1) ? a1B : a1A)[8 * (w & 1) + j], 0.0f);

        // ---- layer 2: 4 K-tiles + bias tile ----
        f32x16 a2A = {}, a2B = {};
#pragma unroll
        for (int w = 0; w < 4; ++w) {
            a2A = __builtin_amdgcn_mfma_f32_32x32x16_bf16(
                *(const bf16x8*)(lb + (30 + 2 * w + 0) * 1024), h1f[w], a2A, 0, 0, 0);
            a2B = __builtin_amdgcn_mfma_f32_32x32x16_bf16(
                *(const bf16x8*)(lb + (30 + 2 * w + 1) * 1024), h1f[w], a2B, 0, 0, 0);
        }
        a2A = __builtin_amdgcn_mfma_f32_32x32x16_bf16(
            *(const bf16x8*)(lb + 38 * 1024), bconst, a2A, 0, 0, 0);
        a2B = __builtin_amdgcn_mfma_f32_32x32x16_bf16(
            *(const bf16x8*)(lb + 39 * 1024), bconst, a2B, 0, 0, 0);

        bf16x8 h2f[4];
#pragma unroll
        for (int w = 0; w < 4; ++w)
#pragma unroll
            for (int j = 0; j < 8; ++j)
                h2f[w][j] = (__bf16)fmaxf(((w >> 1) ? a2B : a2A)[8 * (w & 1) + j], 0.0f);

        // ---- layer 3: 4 K-tiles + bias tile ----
        f32x16 a3A = {}, a3B = {};
#pragma unroll
        for (int w = 0; w < 4; ++w) {
            a3A = __builtin_amdgcn_mfma_f32_32x32x16_bf16(
                *(const bf16x8*)(lb + (40 + 2 * w + 0) * 1024), h2f[w], a3A, 0, 0, 0);
            a3B = __builtin_amdgcn_mfma_f32_32x32x16_bf16(
                *(const bf16x8*)(lb + (40 + 2 * w + 1) * 1024), h2f[w], a3B, 0, 0, 0);
        }
        a3A = __builtin_amdgcn_mfma_f32_32x32x16_bf16(
            *(const bf16x8*)(lb + 48 * 1024), bconst, a3A, 0, 0, 0);
        a3B = __builtin_amdgcn_mfma_f32_32x32x16_bf16(
            *(const bf16x8*)(lb + 49 * 1024), bconst, a3B, 0, 0, 0);

        // ---- store: lane l owns row = rbase + it*256 (col=l&31 folded into rbase) ----
        const int row = rbase + it * 256;
#pragma unroll
        for (int mt = 0; mt < 2; ++mt)
#pragma unroll
            for (int q = 0; q < 4; ++q) {
                const f32x16& a = mt ? a3B : a3A;
                f32x4 v4 = { a[4 * q + 0], a[4 * q + 1], a[4 * q + 2], a[4 * q + 3] };
                __builtin_nontemporal_store(v4,
                    (f32x4*)(out + (size_t)row * 64 + 32 * mt + 8 * q + 4 * h));
            }

#pragma unroll
        for (int d = 0; d < 7; ++d) xc[d] = xn[d];
    }
}

extern "C" void kernel_launch(void* const* d_in, const int* in_sizes, int n_in,
                              void* d_out, int out_size, void* d_ws, size_t ws_size,
                              hipStream_t stream) {
    const float* pos     = (const float*)d_in[0];
    const float* wi      = (const float*)d_in[1];
    const float* rough   = (const float*)d_in[2];
    const float* W1      = (const float*)d_in[3];
    const float* b1      = (const float*)d_in[4];
    const float* W2      = (const float*)d_in[5];
    const float* b2      = (const float*)d_in[6];
    const float* W3      = (const float*)d_in[7];
    const float* b3      = (const float*)d_in[8];
    float* out = (float*)d_out;

    bf16x8* ws = (bf16x8*)d_ws;

    const int n = in_sizes[0] / 3;          // 1048576 rows
    hipLaunchKernelGGL(prep_kernel, dim3(50), dim3(64), 0, stream,
                       W1, b1, W2, b2, W3, b3, ws);
    hipLaunchKernelGGL(cond_net_kernel, dim3(n / 1024), dim3(512), 0, stream,
                       pos, wi, rough, (const bf16x8*)ws, out);
}

// Round 10
// 96.313 us; speedup vs baseline: 1.7058x; 1.7058x over previous
//
#include <hip/hip_runtime.h>

typedef __bf16 bf16x8 __attribute__((ext_vector_type(8)));
typedef __bf16 bf16x4 __attribute__((ext_vector_type(4)));
typedef float  f32x4  __attribute__((ext_vector_type(4)));
typedef float  f32x16 __attribute__((ext_vector_type(16)));

constexpr float K1   = 27.178297f;        // sqrt(512*log2 e); enc = exp2(-(K1*(x-c))^2)
constexpr float STEP = -K1 / 31.0f;       // centers[i] = i/31

// MFMA 32x32x16 bf16 layouts:
//   A-frag: lane l holds A[m=l&31][k=(l>>5)*8+j]
//   B-frag: lane l holds B[k=(l>>5)*8+j][n=l&31]
//   C/D   : lane l reg r holds D[m=(r&3)+8*(r>>2)+4*(l>>5)][n=l&31]  (m74/m101)
//
// Layers 1-2 TRANSPOSED (D[ch][row], row=l&31): enc computed in-lane as B-frag;
// W2 rows pi-permuted so next B-frag is an in-lane repack (r9-verified).
// Layer 3 NON-transposed (D[row][outch], outch=l&31): stores hit full 128B lines.
// L2->L3 handoff: h2[row l&31][ch 16w+8h+j] needs only a lane<->lane+32 exchange:
//   4-run chs {4a..4a+3} live in half h'=a&1, acc (a<8?A:B), regs 4q..4q+3, q=(a>>1)&3.
//   frag_w lo-run a=4w+2h (h'=0 lane), hi-run a+1 (h'=1 lane), both q=(2w+h)&3.
//
// ws frag map (1 KiB each): [0,28) W1 A-frag (t,mt)=2t+mt; [28,30) b1 A-frag;
// [30,38) W2 A-frag pi (w,mt)=30+2w+mt; [38,40) b2; [40,48) W3 B-frag plain (w,mtn).

__global__ void prep_kernel(const float* __restrict__ W1, const float* __restrict__ b1,
                            const float* __restrict__ W2, const float* __restrict__ b2,
                            const float* __restrict__ W3, const float* __restrict__ b3,
                            bf16x8* __restrict__ ws)
{
    const int f = blockIdx.x;
    const int l = threadIdx.x;
    const int h = l >> 5, n = l & 31;
    bf16x8 v = {};
    if (f < 28) {
        const int t = f >> 1, mt = f & 1;
#pragma unroll
        for (int j = 0; j < 8; ++j)
            v[j] = (__bf16)W1[(16 * t + 8 * h + j) * 64 + 32 * mt + n];
    } else if (f < 30) {
        if (h == 0) v[0] = (__bf16)b1[32 * (f - 28) + n];
    } else if (f < 38) {
        const int w = (f - 30) >> 1, mt = (f - 30) & 1;
#pragma unroll
        for (int j = 0; j < 8; ++j)
            v[j] = (__bf16)W2[(16 * w + (j & 3) + 8 * (j >> 2) + 4 * h) * 64 + 32 * mt + n];
    } else if (f < 40) {
        if (h == 0) v[0] = (__bf16)b2[32 * (f - 38) + n];
    } else {
        const int w = (f - 40) >> 1, mtn = (f - 40) & 1;
#pragma unroll
        for (int j = 0; j < 8; ++j)
            v[j] = (__bf16)W3[(16 * w + 8 * h + j) * 64 + 32 * mtn + n];
    }
    ws[f * 64 + l] = v;
}

__device__ __forceinline__ void load_x(const float* __restrict__ pos,
                                       const float* __restrict__ wi,
                                       const float* __restrict__ rough,
                                       int row, float* x)
{
    x[0] = pos[row * 3 + 0]; x[1] = pos[row * 3 + 1]; x[2] = pos[row * 3 + 2];
    x[3] = wi[row * 3 + 0];  x[4] = wi[row * 3 + 1];  x[5] = wi[row * 3 + 2];
    x[6] = rough[row];
}

// 8 waves x 32 rows/iter x 4 iters = 1024 rows/block
__global__ __launch_bounds__(512, 4)
void cond_net_kernel(const float* __restrict__ pos, const float* __restrict__ wi,
                     const float* __restrict__ rough,
                     const float* __restrict__ b3,
                     const bf16x8* __restrict__ ws,
                     float* __restrict__ out)
{
    __shared__ __align__(16) char lds[48 * 1024];

    const int tid = threadIdx.x;
    const int l = tid & 63, wv = tid >> 6, h = l >> 5, n = l & 31;

    // stage all 48 fragments via async global->LDS, lane-linear
    for (int fr = wv; fr < 48; fr += 8)
        __builtin_amdgcn_global_load_lds(
            (const __attribute__((address_space(1))) void*)(ws + fr * 64 + l),
            (__attribute__((address_space(3))) void*)(lds + fr * 1024),
            16, 0, 0);

    // bias B-frag for layers 1-2: 1.0 at slot (h=0, j=0)
    bf16x8 bconst = {};
    bconst[0] = (h == 0) ? (__bf16)1.0f : (__bf16)0.0f;

    // layer-3 biases: per-lane scalars (splat into acc init)
    const float b3A = b3[n], b3B = b3[n + 32];

    const float hoff = STEP * (float)(8 * h);
    const int rbin = blockIdx.x * 1024 + wv * 32 + n;     // input row for this lane

    float xc[7];
    load_x(pos, wi, rough, rbin, xc);

    __syncthreads();   // drains global_load_lds + barrier

    unsigned int ldsoff = 0;
#pragma unroll 1
    for (int it = 0; it < 4; ++it) {
        asm volatile("" : "+v"(ldsoff));          // defeat LICM on LDS reads
        const char* lb = (const char*)lds + ldsoff + l * 16;

        // prefetch next iteration's inputs
        float xn[7];
        load_x(pos, wi, rough, rbin + ((it + 1) & 3) * 256, xn);

        float B0[7];
#pragma unroll
        for (int d = 0; d < 7; ++d)
            B0[d] = fmaf(K1, fminf(fmaxf(xc[d], 0.0f), 1.0f), hoff);

        // ---- layer 1 (transposed): 14 K-tiles + bias tile ----
        f32x16 a1A = {}, a1B = {};
#pragma unroll
        for (int t = 0; t < 14; ++t) {
            const int kk = t >> 1, wh = t & 1;
            bf16x8 e;
#pragma unroll
            for (int j = 0; j < 8; ++j) {
                const float d = fmaf((float)(16 * wh + j), STEP, B0[kk]);
                e[j] = (__bf16)__builtin_amdgcn_exp2f(-(d * d));
            }
            a1A = __builtin_amdgcn_mfma_f32_32x32x16_bf16(
                *(const bf16x8*)(lb + (2 * t + 0) * 1024), e, a1A, 0, 0, 0);
            a1B = __builtin_amdgcn_mfma_f32_32x32x16_bf16(
                *(const bf16x8*)(lb + (2 * t + 1) * 1024), e, a1B, 0, 0, 0);
        }
        a1A = __builtin_amdgcn_mfma_f32_32x32x16_bf16(
            *(const bf16x8*)(lb + 28 * 1024), bconst, a1A, 0, 0, 0);
        a1B = __builtin_amdgcn_mfma_f32_32x32x16_bf16(
            *(const bf16x8*)(lb + 29 * 1024), bconst, a1B, 0, 0, 0);

        // ---- relu + in-lane repack (r9-verified) ----
        bf16x8 h1f[4];
#pragma unroll
        for (int w = 0; w < 4; ++w)
#pragma unroll
            for (int j = 0; j < 8; ++j)
                h1f[w][j] = (__bf16)fmaxf(((w >> 1) ? a1B : a1A)[8 * (w & 1) + j], 0.0f);

        // ---- layer 2 (transposed): 4 K-tiles + bias tile ----
        f32x16 a2A = {}, a2B = {};
#pragma unroll
        for (int w = 0; w < 4; ++w) {
            a2A = __builtin_amdgcn_mfma_f32_32x32x16_bf16(
                *(const bf16x8*)(lb + (30 + 2 * w + 0) * 1024), h1f[w], a2A, 0, 0, 0);
            a2B = __builtin_amdgcn_mfma_f32_32x32x16_bf16(
                *(const bf16x8*)(lb + (30 + 2 * w + 1) * 1024), h1f[w], a2B, 0, 0, 0);
        }
        a2A = __builtin_amdgcn_mfma_f32_32x32x16_bf16(
            *(const bf16x8*)(lb + 38 * 1024), bconst, a2A, 0, 0, 0);
        a2B = __builtin_amdgcn_mfma_f32_32x32x16_bf16(
            *(const bf16x8*)(lb + 39 * 1024), bconst, a2B, 0, 0, 0);

        // ---- relu + pack acc2 to bf16 pairs: pk[X][q] = chs {8q+4h'..} of own half ----
        unsigned int pku[2][4][2];
#pragma unroll
        for (int X = 0; X < 2; ++X)
#pragma unroll
            for (int q = 0; q < 4; ++q) {
                bf16x4 t;
#pragma unroll
                for (int i = 0; i < 4; ++i)
                    t[i] = (__bf16)fmaxf((X ? a2B : a2A)[4 * q + i], 0.0f);
                union { bf16x4 b; unsigned int u[2]; } c; c.b = t;
                pku[X][q][0] = c.u[0]; pku[X][q][1] = c.u[1];
            }

        // ---- half-wave exchange: h=0 sends odd-q, receives even-q (and vice versa) ----
        unsigned int rcv[2][2][2];
#pragma unroll
        for (int X = 0; X < 2; ++X)
#pragma unroll
            for (int i = 0; i < 2; ++i)
#pragma unroll
                for (int u = 0; u < 2; ++u) {
                    const unsigned int snd = h ? pku[X][2 * i][u] : pku[X][2 * i + 1][u];
                    rcv[X][i][u] = (unsigned int)__shfl_xor((int)snd, 32, 64);
                }

        // ---- layer 3 (non-transposed): A = h2 frags, B = W3 from LDS ----
        f32x16 a3A, a3B;
#pragma unroll
        for (int r = 0; r < 16; ++r) { a3A[r] = b3A; a3B[r] = b3B; }

#pragma unroll
        for (int w = 0; w < 4; ++w) {
            const int X = w >> 1, i = w & 1;
            union { unsigned int u[4]; bf16x8 f; } fr;
            fr.u[0] = h ? rcv[X][i][0]        : pku[X][2 * i][0];
            fr.u[1] = h ? rcv[X][i][1]        : pku[X][2 * i][1];
            fr.u[2] = h ? pku[X][2 * i + 1][0] : rcv[X][i][0];
            fr.u[3] = h ? pku[X][2 * i + 1][1] : rcv[X][i][1];
            a3A = __builtin_amdgcn_mfma_f32_32x32x16_bf16(
                fr.f, *(const bf16x8*)(lb + (40 + 2 * w + 0) * 1024), a3A, 0, 0, 0);
            a3B = __builtin_amdgcn_mfma_f32_32x32x16_bf16(
                fr.f, *(const bf16x8*)(lb + (40 + 2 * w + 1) * 1024), a3B, 0, 0, 0);
        }

        // ---- store: D3[row][outch], outch = n -> full 128B lines per instruction ----
        const int rowbase = blockIdx.x * 1024 + it * 256 + wv * 32;
#pragma unroll
        for (int r = 0; r < 16; ++r) {
            const int m = (r & 3) + 8 * (r >> 2) + 4 * h;
            float* p = out + (size_t)(rowbase + m) * 64 + n;
            __builtin_nontemporal_store(a3A[r], p);
            __builtin_nontemporal_store(a3B[r], p + 32);
        }

#pragma unroll
        for (int d = 0; d < 7; ++d) xc[d] = xn[d];
    }
}

extern "C" void kernel_launch(void* const* d_in, const int* in_sizes, int n_in,
                              void* d_out, int out_size, void* d_ws, size_t ws_size,
                              hipStream_t stream) {
    const float* pos     = (const float*)d_in[0];
    const float* wi      = (const float*)d_in[1];
    const float* rough   = (const float*)d_in[2];
    const float* W1      = (const float*)d_in[3];
    const float* b1      = (const float*)d_in[4];
    const float* W2      = (const float*)d_in[5];
    const float* b2      = (const float*)d_in[6];
    const float* W3      = (const float*)d_in[7];
    const float* b3      = (const float*)d_in[8];
    float* out = (float*)d_out;

    bf16x8* ws = (bf16x8*)d_ws;

    const int n = in_sizes[0] / 3;          // 1048576 rows
    hipLaunchKernelGGL(prep_kernel, dim3(48), dim3(64), 0, stream,
                       W1, b1, W2, b2, W3, b3, ws);
    hipLaunchKernelGGL(cond_net_kernel, dim3(n / 1024), dim3(512), 0, stream,
                       pos, wi, rough, b3, (const bf16x8*)ws, out);
}